// Round 1
// 973.083 us; speedup vs baseline: 1.1107x; 1.1107x over previous
//
#include <hip/hip_runtime.h>

#define DEV __device__ __forceinline__

namespace {

constexpr int B_ = 8;
constexpr int N_ = 1024;
constexpr int M_ = 256;
constexpr int D_ = 25;
constexpr int FH_ = 240;
constexpr int NATOM = B_ * N_;          // 8192
constexpr float CSC = 1.0f / 256.0f;    // 4/(NN*NTYPES*4)

DEV float fast_tanh(float x) {
  float ax = fabsf(x);
  float e = __expf(-2.0f * ax);
  float r = (1.0f - e) * __builtin_amdgcn_rcpf(1.0f + e);
  return copysignf(r, x);
}

// Scalar geometry pieces shared by descriptor and Jacobian.
struct Geom {
  float mf, inr, inr2, inr4, inr3, vv, dvv;
};

DEV Geom geom_core(float dx, float dy, float dz, int nb) {
  Geom g;
  g.mf = (nb > 0) ? 1.0f : 0.0f;
  float dr2 = dx * dx + dy * dy + dz * dz;
  float safe = (nb > 0) ? dr2 : 1.0f;
  float rs = __builtin_amdgcn_rsqf(safe);   // 1/sqrt(safe)
  float rij = safe * rs;                    // sqrt(safe)
  g.inr = g.mf * rs;
  float x = rij * g.mf;
  g.inr2 = g.inr * g.inr;
  g.inr4 = g.inr2 * g.inr2;
  g.inr3 = g.inr4 * x;
  float u = (x - 5.8f) * 5.0f;              // (x-RMIN)/(RMAX-RMIN)
  float uu = u * u;
  float A = -6.0f * uu + 15.0f * u - 10.0f;
  float poly = uu * u * A + 1.0f;
  float dpoly = (3.0f * uu * A + uu * u * (-12.0f * u + 15.0f)) * 5.0f;
  bool mid = (x >= 5.8f) && (x < 6.0f);
  g.vv = ((x < 5.8f) ? 1.0f : (mid ? poly : 0.0f)) * g.mf;
  g.dvv = (mid ? dpoly : 0.0f) * g.mf;
  return g;
}

// Normalized descriptor channels blk[4]; also returns 1/dstd per channel.
DEV void geom_blk(const Geom& g, float dx, float dy, float dz, int t, int m,
                  const float* __restrict__ davg, const float* __restrict__ dstd,
                  float* __restrict__ blk, float* __restrict__ rsv) {
  int bidx = (t * M_ + m) * 4;
  float4 av = *(const float4*)(davg + bidx);
  float4 sv = *(const float4*)(dstd + bidx);
  float pre[4] = {g.inr, dx * g.inr2, dy * g.inr2, dz * g.inr2};
  float avf[4] = {av.x, av.y, av.z, av.w};
  float svf[4] = {sv.x, sv.y, sv.z, sv.w};
#pragma unroll
  for (int d = 0; d < 4; ++d) {
    rsv[d] = __builtin_amdgcn_rcpf(svf[d]);
    blk[d] = (pre[d] * g.vv - avf[d]) * rsv[d];
  }
}

// K1: per atom (block), per neighbor (thread): geometry + lean embedding fwd
// (only G survives; h overwritten in place -> ~60 live floats, no spills),
// then acc[4][25] = CSC * sum_m blk[m][d] * G[m][e] via LDS reduction.
__global__ __launch_bounds__(256) __attribute__((amdgpu_waves_per_eu(2, 4)))
void k_embed_acc(
    const float* __restrict__ dR, const int* __restrict__ neigh,
    const float* __restrict__ davg, const float* __restrict__ dstd,
    const float* __restrict__ eW0, const float* __restrict__ eb0,
    const float* __restrict__ eW1, const float* __restrict__ eb1,
    const float* __restrict__ eW2, const float* __restrict__ eb2,
    float* __restrict__ acc_ws) {
  __shared__ float sG[M_ * D_];
  __shared__ float4 sBlk[M_];
  int atom = blockIdx.x;
  int n = atom & (N_ - 1);
  int t = (n >= 512) ? 1 : 0;
  int m = threadIdx.x;
  // pair index is uniform across each 64-lane wave (m>>7 constant per wave)
  int p = __builtin_amdgcn_readfirstlane(t * 2 + (m >> 7));
  const float* W0 = eW0 + p * D_;
  const float* b0 = eb0 + p * D_;
  const float* W1 = eW1 + p * D_ * D_;
  const float* b1 = eb1 + p * D_;
  const float* W2 = eW2 + p * D_ * D_;
  const float* b2 = eb2 + p * D_;
  int base = atom * M_ + m;
  float dx = dR[base * 3 + 0];
  float dy = dR[base * 3 + 1];
  float dz = dR[base * 3 + 2];
  int nb = neigh[base];
  Geom g = geom_core(dx, dy, dz, nb);
  float blk[4], rsv[4];
  geom_blk(g, dx, dy, dz, t, m, davg, dstd, blk, rsv);
  float s = blk[0];
  float h[D_], a[D_];
#pragma unroll
  for (int e = 0; e < D_; ++e) h[e] = fast_tanh(fmaf(s, W0[e], b0[e]));
#pragma unroll
  for (int e = 0; e < D_; ++e) a[e] = b1[e];
#pragma unroll
  for (int f = 0; f < D_; ++f) {
    float hf = h[f];
#pragma unroll
    for (int e = 0; e < D_; ++e) a[e] = fmaf(hf, W1[f * D_ + e], a[e]);
  }
#pragma unroll
  for (int e = 0; e < D_; ++e) h[e] += fast_tanh(a[e]);   // h1
#pragma unroll
  for (int e = 0; e < D_; ++e) a[e] = b2[e];
#pragma unroll
  for (int f = 0; f < D_; ++f) {
    float hf = h[f];
#pragma unroll
    for (int e = 0; e < D_; ++e) a[e] = fmaf(hf, W2[f * D_ + e], a[e]);
  }
#pragma unroll
  for (int e = 0; e < D_; ++e) sG[m * D_ + e] = h[e] + fast_tanh(a[e]);  // G
  sBlk[m] = make_float4(blk[0], blk[1], blk[2], blk[3]);
  __syncthreads();
  if (threadIdx.x < 100) {
    int d = threadIdx.x & 3;
    int e = threadIdx.x >> 2;
    const float* sb = (const float*)sBlk;
    float sum = 0.0f;
    for (int mm = 0; mm < M_; ++mm)
      sum = fmaf(sb[mm * 4 + d], sG[mm * D_ + e], sum);
    acc_ws[atom * 100 + d * D_ + e] = sum * CSC;
  }
}

// K2: 8 atoms per block. DRt + fitting net fwd + bwd, emits Ei/Etot and dacc.
__global__ __launch_bounds__(256) void k_fit(
    const float* __restrict__ acc_ws,
    const float* __restrict__ fW0, const float* __restrict__ fb0,
    const float* __restrict__ fW1, const float* __restrict__ fb1,
    const float* __restrict__ fW2, const float* __restrict__ fb2,
    const float* __restrict__ fW3, const float* __restrict__ fb3,
    const float* __restrict__ ener_shift,
    float* __restrict__ dacc_ws, float* __restrict__ out) {
  constexpr int AB = 8;
  __shared__ float sAcc[AB][100];
  __shared__ float sX[AB][400];   // x fwd, then dx bwd
  __shared__ float sH0[AB][FH_];  // h0, then g0
  __shared__ float sT1[AB][FH_];  // tanh1, then g1
  __shared__ float sH1[AB][FH_];  // h1, then dh1
  __shared__ float sT2[AB][FH_];  // tanh2, then g2
  __shared__ float sEi[AB];
  int a0 = blockIdx.x * AB;
  int bb = a0 >> 10;
  int n0 = a0 & (N_ - 1);
  int t = (n0 >= 512) ? 1 : 0;
  int tid = threadIdx.x;
  for (int idx = tid; idx < AB * 100; idx += 256)
    ((float*)sAcc)[idx] = acc_ws[a0 * 100 + idx];
  if (tid < AB) sEi[tid] = 0.0f;
  __syncthreads();
  // DRt[e][f] = sum_d acc[d][e]*acc[d][f], f<16
  for (int idx = tid; idx < AB * 400; idx += 256) {
    int a = idx / 400; int r = idx % 400; int e = r >> 4; int f = r & 15;
    const float* A = sAcc[a];
    sX[a][r] = A[e] * A[f] + A[25 + e] * A[25 + f] + A[50 + e] * A[50 + f] +
               A[75 + e] * A[75 + f];
  }
  __syncthreads();
  const float* W0 = fW0 + t * 400 * FH_;
  const float* W1 = fW1 + t * FH_ * FH_;
  const float* W2 = fW2 + t * FH_ * FH_;
  const float* B0 = fb0 + t * FH_;
  const float* B1 = fb1 + t * FH_;
  const float* B2 = fb2 + t * FH_;
  const float* W3 = fW3 + t * FH_;
  int j = tid;
  if (j < FH_) {  // layer 0: 400 -> 240
    float acc8[AB];
#pragma unroll
    for (int a = 0; a < AB; ++a) acc8[a] = B0[j];
    for (int i = 0; i < 400; ++i) {
      float w = W0[i * FH_ + j];
#pragma unroll
      for (int a = 0; a < AB; ++a) acc8[a] = fmaf(sX[a][i], w, acc8[a]);
    }
#pragma unroll
    for (int a = 0; a < AB; ++a) sH0[a][j] = fast_tanh(acc8[a]);
  }
  __syncthreads();
  if (j < FH_) {  // layer 1 (residual)
    float acc8[AB];
#pragma unroll
    for (int a = 0; a < AB; ++a) acc8[a] = B1[j];
    for (int f = 0; f < FH_; ++f) {
      float w = W1[f * FH_ + j];
#pragma unroll
      for (int a = 0; a < AB; ++a) acc8[a] = fmaf(sH0[a][f], w, acc8[a]);
    }
#pragma unroll
    for (int a = 0; a < AB; ++a) {
      float tv = fast_tanh(acc8[a]);
      sT1[a][j] = tv;
      sH1[a][j] = sH0[a][j] + tv;
    }
  }
  __syncthreads();
  if (j < FH_) {  // layer 2 (residual) + Ei dot
    float acc8[AB];
#pragma unroll
    for (int a = 0; a < AB; ++a) acc8[a] = B2[j];
    for (int f = 0; f < FH_; ++f) {
      float w = W2[f * FH_ + j];
#pragma unroll
      for (int a = 0; a < AB; ++a) acc8[a] = fmaf(sH1[a][f], w, acc8[a]);
    }
    float w3 = W3[j];
#pragma unroll
    for (int a = 0; a < AB; ++a) {
      float tv = fast_tanh(acc8[a]);
      sT2[a][j] = tv;
      atomicAdd(&sEi[a], (sH1[a][j] + tv) * w3);
    }
  }
  __syncthreads();
  if (tid < AB) {
    float ei = sEi[tid] + fb3[t] + ener_shift[t];
    out[8 + a0 + tid] = ei;            // Ei
    atomicAdd(&out[bb], ei);           // Etot
  }
  if (j < FH_) {  // g2 = W3 * (1 - t2^2)   (dEi = 1)
    float w3 = W3[j];
#pragma unroll
    for (int a = 0; a < AB; ++a) {
      float tv = sT2[a][j];
      sT2[a][j] = w3 * (1.0f - tv * tv);
    }
  }
  __syncthreads();
  if (j < FH_) {  // dh1 = W3 + g2 @ W2^T ; g1 = dh1*(1-t1^2)
    float w3 = W3[j];
    float acc8[AB];
#pragma unroll
    for (int a = 0; a < AB; ++a) acc8[a] = w3;
    for (int k = 0; k < FH_; ++k) {
      float w = W2[j * FH_ + k];
#pragma unroll
      for (int a = 0; a < AB; ++a) acc8[a] = fmaf(sT2[a][k], w, acc8[a]);
    }
#pragma unroll
    for (int a = 0; a < AB; ++a) {
      float dh1 = acc8[a];
      float tv = sT1[a][j];
      sH1[a][j] = dh1;
      sT1[a][j] = dh1 * (1.0f - tv * tv);
    }
  }
  __syncthreads();
  if (j < FH_) {  // dh0 = dh1 + g1 @ W1^T ; g0 = dh0*(1-h0^2)
    float acc8[AB];
#pragma unroll
    for (int a = 0; a < AB; ++a) acc8[a] = sH1[a][j];
    for (int k = 0; k < FH_; ++k) {
      float w = W1[j * FH_ + k];
#pragma unroll
      for (int a = 0; a < AB; ++a) acc8[a] = fmaf(sT1[a][k], w, acc8[a]);
    }
#pragma unroll
    for (int a = 0; a < AB; ++a) {
      float h0v = sH0[a][j];
      sH0[a][j] = acc8[a] * (1.0f - h0v * h0v);
    }
  }
  __syncthreads();
  // dx = g0 @ W0^T  (overwrite sX)
  for (int i = tid; i < 400; i += 256) {
    float acc8[AB];
#pragma unroll
    for (int a = 0; a < AB; ++a) acc8[a] = 0.0f;
    for (int jj = 0; jj < FH_; ++jj) {
      float w = W0[i * FH_ + jj];
#pragma unroll
      for (int a = 0; a < AB; ++a) acc8[a] = fmaf(sH0[a][jj], w, acc8[a]);
    }
#pragma unroll
    for (int a = 0; a < AB; ++a) sX[a][i] = acc8[a];
  }
  __syncthreads();
  // dacc[d][e] = sum_{f<16} dDRt[e][f]*acc[d][f] + [e<16] sum_e2 dDRt[e2][e]*acc[d][e2]
  for (int idx = tid; idx < AB * 100; idx += 256) {
    int a = idx / 100; int r = idx % 100; int d = r / 25; int e = r % 25;
    const float* A = sAcc[a];
    const float* DX = sX[a];
    float sum = 0.0f;
#pragma unroll
    for (int f = 0; f < 16; ++f) sum = fmaf(DX[e * 16 + f], A[d * 25 + f], sum);
    if (e < 16) {
#pragma unroll
      for (int e2 = 0; e2 < 25; ++e2) sum = fmaf(DX[e2 * 16 + e], A[d * 25 + e2], sum);
    }
    dacc_ws[a0 * 100 + idx] = sum;
  }
}

// K3: per atom (block), per neighbor (thread).
// Key change vs previous version: the embedding MLP input is a SCALAR, so the
// reverse-mode VJP (which kept h0/t1/h1/t2 alive across a backward sweep,
// ~150 live floats -> spilled at VGPR_Count=80, 219 MB scratch writes) is
// replaced by forward-mode JVP interleaved with the forward pass: carry
// (h, dh/ds) per layer. ds = sum_e dGrad[e]*G'[e]. Same FLOPs, peak live
// ~100 floats. waves_per_eu(2,2) pins the allocator to a 256-VGPR budget so
// it cannot trade spills for occupancy again.
__global__ __launch_bounds__(256) __attribute__((amdgpu_waves_per_eu(2, 2)))
void k_bwd_force(
    const float* __restrict__ dR, const int* __restrict__ neigh,
    const float* __restrict__ davg, const float* __restrict__ dstd,
    const float* __restrict__ eW0, const float* __restrict__ eb0,
    const float* __restrict__ eW1, const float* __restrict__ eb1,
    const float* __restrict__ eW2, const float* __restrict__ eb2,
    const float* __restrict__ dacc_ws, float* __restrict__ out) {
  int atom = blockIdx.x;
  int bb = atom >> 10;
  int n = atom & (N_ - 1);
  int t = (n >= 512) ? 1 : 0;
  int m = threadIdx.x;
  int p = __builtin_amdgcn_readfirstlane(t * 2 + (m >> 7));
  const float* W0 = eW0 + p * D_;
  const float* b0 = eb0 + p * D_;
  const float* W1 = eW1 + p * D_ * D_;
  const float* b1 = eb1 + p * D_;
  const float* W2 = eW2 + p * D_ * D_;
  const float* b2 = eb2 + p * D_;
  const float* dac = dacc_ws + atom * 100;  // block-uniform -> scalar loads
  int base = atom * M_ + m;
  float dx = dR[base * 3 + 0];
  float dy = dR[base * 3 + 1];
  float dz = dR[base * 3 + 2];
  int nb = neigh[base];
  Geom g = geom_core(dx, dy, dz, nb);
  float blk[4], rsv[4];
  geom_blk(g, dx, dy, dz, t, m, davg, dstd, blk, rsv);

  // ---- fused forward + d/ds (JVP) through the embedding MLP ----
  float s = blk[0];
  float h[D_], hp[D_];          // value, d/ds
#pragma unroll
  for (int e = 0; e < D_; ++e) {
    float th = fast_tanh(fmaf(s, W0[e], b0[e]));
    h[e] = th;
    hp[e] = (1.0f - th * th) * W0[e];
  }
  {  // layer 1 (residual)
    float a[D_], ap[D_];
#pragma unroll
    for (int e = 0; e < D_; ++e) { a[e] = b1[e]; ap[e] = 0.0f; }
#pragma unroll
    for (int f = 0; f < D_; ++f) {
      float hf = h[f], gf = hp[f];
#pragma unroll
      for (int e = 0; e < D_; ++e) {
        float w = W1[f * D_ + e];
        a[e] = fmaf(hf, w, a[e]);
        ap[e] = fmaf(gf, w, ap[e]);
      }
    }
#pragma unroll
    for (int e = 0; e < D_; ++e) {
      float th = fast_tanh(a[e]);
      h[e] += th;
      hp[e] = fmaf(1.0f - th * th, ap[e], hp[e]);
    }
  }
  {  // layer 2 (residual) -> h = G, hp = dG/ds
    float a[D_], ap[D_];
#pragma unroll
    for (int e = 0; e < D_; ++e) { a[e] = b2[e]; ap[e] = 0.0f; }
#pragma unroll
    for (int f = 0; f < D_; ++f) {
      float hf = h[f], gf = hp[f];
#pragma unroll
      for (int e = 0; e < D_; ++e) {
        float w = W2[f * D_ + e];
        a[e] = fmaf(hf, w, a[e]);
        ap[e] = fmaf(gf, w, ap[e]);
      }
    }
#pragma unroll
    for (int e = 0; e < D_; ++e) {
      float th = fast_tanh(a[e]);
      h[e] += th;
      hp[e] = fmaf(1.0f - th * th, ap[e], hp[e]);
    }
  }

  // ---- gradients: dE[d] = CSC*(sum_e dac[d][e]*G[e]) + [d==0] ds ----
  // ds = sum_e dGrad[e]*G'[e],  dGrad[e] = CSC * sum_d dac[d][e]*blk[d]
  float ds = 0.0f, db0 = 0.0f, db1 = 0.0f, db2 = 0.0f, db3 = 0.0f;
#pragma unroll
  for (int e = 0; e < D_; ++e) {
    float d0 = dac[e], d1 = dac[25 + e], d2 = dac[50 + e], d3 = dac[75 + e];
    float gG = d0 * blk[0] + d1 * blk[1] + d2 * blk[2] + d3 * blk[3];
    ds = fmaf(gG, hp[e], ds);
    float he = h[e];
    db0 = fmaf(d0, he, db0);
    db1 = fmaf(d1, he, db1);
    db2 = fmaf(d2, he, db2);
    db3 = fmaf(d3, he, db3);
  }
  float dE0 = (db0 + ds) * CSC;
  float dE1 = db1 * CSC, dE2 = db2 * CSC, dE3 = db3 * CSC;

  // ---- fold the 4x3 geometry Jacobian directly into the force vector ----
  float dv[3] = {dx, dy, dz};
  float pre1[3] = {dx * g.inr2, dy * g.inr2, dz * g.inr2};
  float ci = g.dvv * g.inr;
  float com[3];
#pragma unroll
  for (int c = 0; c < 3; ++c) com[c] = ci * dv[c];
  float iv = g.inr3 * g.vv;
  float pc[3];
  float f0 = dE0 * rsv[0];
#pragma unroll
  for (int c = 0; c < 3; ++c) pc[c] = f0 * (dv[c] * iv - g.inr * com[c]);
  float dEr[3] = {dE1, dE2, dE3};
#pragma unroll
  for (int r = 0; r < 3; ++r) {
    float fr = dEr[r] * rsv[1 + r];
#pragma unroll
    for (int c = 0; c < 3; ++c) {
      float outer = 2.0f * dv[r] * dv[c] * g.inr4 - ((r == c) ? g.inr2 : 0.0f);
      pc[c] = fmaf(fr, outer * g.vv - pre1[r] * com[c], pc[c]);
    }
  }
  float px = pc[0] * g.mf, py = pc[1] * g.mf, pz = pc[2] * g.mf;

  if (nb > 0) {  // scatter to neighbor j = nb-1
    int jn = nb - 1;
    int fi = 8 + NATOM + (bb * N_ + jn) * 3;
    atomicAdd(&out[fi + 0], px);
    atomicAdd(&out[fi + 1], py);
    atomicAdd(&out[fi + 2], pz);
  }
  // F_self: 64-lane shuffle reduce, one atomic per wave per component
#pragma unroll
  for (int i = 1; i < 64; i <<= 1) {
    px += __shfl_xor(px, i);
    py += __shfl_xor(py, i);
    pz += __shfl_xor(pz, i);
  }
  if ((m & 63) == 0) {
    int fi = 8 + NATOM + atom * 3;
    atomicAdd(&out[fi + 0], -px);
    atomicAdd(&out[fi + 1], -py);
    atomicAdd(&out[fi + 2], -pz);
  }
}

}  // namespace

extern "C" void kernel_launch(void* const* d_in, const int* in_sizes, int n_in,
                              void* d_out, int out_size, void* d_ws, size_t ws_size,
                              hipStream_t stream) {
  (void)in_sizes; (void)n_in; (void)ws_size;
  const float* image_dR   = (const float*)d_in[0];
  const int*   list_neigh = (const int*)d_in[1];
  const float* davg       = (const float*)d_in[2];
  const float* dstd       = (const float*)d_in[3];
  const float* eW0        = (const float*)d_in[4];
  const float* eb0        = (const float*)d_in[5];
  const float* eW1        = (const float*)d_in[6];
  const float* eb1        = (const float*)d_in[7];
  const float* eW2        = (const float*)d_in[8];
  const float* eb2        = (const float*)d_in[9];
  const float* fW0        = (const float*)d_in[10];
  const float* fb0        = (const float*)d_in[11];
  const float* fW1        = (const float*)d_in[12];
  const float* fb1        = (const float*)d_in[13];
  const float* fW2        = (const float*)d_in[14];
  const float* fb2        = (const float*)d_in[15];
  const float* fW3        = (const float*)d_in[16];
  const float* fb3        = (const float*)d_in[17];
  const float* ener_shift = (const float*)d_in[18];
  float* out = (float*)d_out;
  float* acc_ws  = (float*)d_ws;                  // 8192*100 floats
  float* dacc_ws = acc_ws + NATOM * 100;          // 8192*100 floats

  hipMemsetAsync(d_out, 0, (size_t)out_size * sizeof(float), stream);
  k_embed_acc<<<NATOM, 256, 0, stream>>>(image_dR, list_neigh, davg, dstd,
                                         eW0, eb0, eW1, eb1, eW2, eb2, acc_ws);
  k_fit<<<NATOM / 8, 256, 0, stream>>>(acc_ws, fW0, fb0, fW1, fb1, fW2, fb2,
                                       fW3, fb3, ener_shift, dacc_ws, out);
  k_bwd_force<<<NATOM, 256, 0, stream>>>(image_dR, list_neigh, davg, dstd,
                                         eW0, eb0, eW1, eb1, eW2, eb2,
                                         dacc_ws, out);
}

// Round 2
// 942.448 us; speedup vs baseline: 1.1468x; 1.0325x over previous
//
#include <hip/hip_runtime.h>

#define DEV __device__ __forceinline__

namespace {

constexpr int B_ = 8;
constexpr int N_ = 1024;
constexpr int M_ = 256;
constexpr int D_ = 25;
constexpr int FH_ = 240;
constexpr int NATOM = B_ * N_;          // 8192
constexpr float CSC = 1.0f / 256.0f;    // 4/(NN*NTYPES*4)

DEV float fast_tanh(float x) {
  float ax = fabsf(x);
  float e = __expf(-2.0f * ax);
  float r = (1.0f - e) * __builtin_amdgcn_rcpf(1.0f + e);
  return copysignf(r, x);
}

// Scalar geometry pieces shared by descriptor and Jacobian.
struct Geom {
  float mf, inr, inr2, inr4, inr3, vv, dvv;
};

DEV Geom geom_core(float dx, float dy, float dz, int nb) {
  Geom g;
  g.mf = (nb > 0) ? 1.0f : 0.0f;
  float dr2 = dx * dx + dy * dy + dz * dz;
  float safe = (nb > 0) ? dr2 : 1.0f;
  float rs = __builtin_amdgcn_rsqf(safe);   // 1/sqrt(safe)
  float rij = safe * rs;                    // sqrt(safe)
  g.inr = g.mf * rs;
  float x = rij * g.mf;
  g.inr2 = g.inr * g.inr;
  g.inr4 = g.inr2 * g.inr2;
  g.inr3 = g.inr4 * x;
  float u = (x - 5.8f) * 5.0f;              // (x-RMIN)/(RMAX-RMIN)
  float uu = u * u;
  float A = -6.0f * uu + 15.0f * u - 10.0f;
  float poly = uu * u * A + 1.0f;
  float dpoly = (3.0f * uu * A + uu * u * (-12.0f * u + 15.0f)) * 5.0f;
  bool mid = (x >= 5.8f) && (x < 6.0f);
  g.vv = ((x < 5.8f) ? 1.0f : (mid ? poly : 0.0f)) * g.mf;
  g.dvv = (mid ? dpoly : 0.0f) * g.mf;
  return g;
}

// Normalized descriptor channels blk[4]; also returns 1/dstd per channel.
DEV void geom_blk(const Geom& g, float dx, float dy, float dz, int t, int m,
                  const float* __restrict__ davg, const float* __restrict__ dstd,
                  float* __restrict__ blk, float* __restrict__ rsv) {
  int bidx = (t * M_ + m) * 4;
  float4 av = *(const float4*)(davg + bidx);
  float4 sv = *(const float4*)(dstd + bidx);
  float pre[4] = {g.inr, dx * g.inr2, dy * g.inr2, dz * g.inr2};
  float avf[4] = {av.x, av.y, av.z, av.w};
  float svf[4] = {sv.x, sv.y, sv.z, sv.w};
#pragma unroll
  for (int d = 0; d < 4; ++d) {
    rsv[d] = __builtin_amdgcn_rcpf(svf[d]);
    blk[d] = (pre[d] * g.vv - avf[d]) * rsv[d];
  }
}

// K1: per atom (block), per neighbor (thread): geometry + lean embedding fwd
// (only G survives; h overwritten in place -> ~60 live floats, no spills),
// then acc[4][25] = CSC * sum_m blk[m][d] * G[m][e] via LDS reduction.
__global__ __launch_bounds__(256) __attribute__((amdgpu_waves_per_eu(2, 4)))
void k_embed_acc(
    const float* __restrict__ dR, const int* __restrict__ neigh,
    const float* __restrict__ davg, const float* __restrict__ dstd,
    const float* __restrict__ eW0, const float* __restrict__ eb0,
    const float* __restrict__ eW1, const float* __restrict__ eb1,
    const float* __restrict__ eW2, const float* __restrict__ eb2,
    float* __restrict__ acc_ws) {
  __shared__ float sG[M_ * D_];
  __shared__ float4 sBlk[M_];
  int atom = blockIdx.x;
  int n = atom & (N_ - 1);
  int t = (n >= 512) ? 1 : 0;
  int m = threadIdx.x;
  // pair index is uniform across each 64-lane wave (m>>7 constant per wave)
  int p = __builtin_amdgcn_readfirstlane(t * 2 + (m >> 7));
  const float* W0 = eW0 + p * D_;
  const float* b0 = eb0 + p * D_;
  const float* W1 = eW1 + p * D_ * D_;
  const float* b1 = eb1 + p * D_;
  const float* W2 = eW2 + p * D_ * D_;
  const float* b2 = eb2 + p * D_;
  int base = atom * M_ + m;
  float dx = dR[base * 3 + 0];
  float dy = dR[base * 3 + 1];
  float dz = dR[base * 3 + 2];
  int nb = neigh[base];
  Geom g = geom_core(dx, dy, dz, nb);
  float blk[4], rsv[4];
  geom_blk(g, dx, dy, dz, t, m, davg, dstd, blk, rsv);
  float s = blk[0];
  float h[D_], a[D_];
#pragma unroll
  for (int e = 0; e < D_; ++e) h[e] = fast_tanh(fmaf(s, W0[e], b0[e]));
#pragma unroll
  for (int e = 0; e < D_; ++e) a[e] = b1[e];
#pragma unroll
  for (int f = 0; f < D_; ++f) {
    float hf = h[f];
#pragma unroll
    for (int e = 0; e < D_; ++e) a[e] = fmaf(hf, W1[f * D_ + e], a[e]);
  }
#pragma unroll
  for (int e = 0; e < D_; ++e) h[e] += fast_tanh(a[e]);   // h1
#pragma unroll
  for (int e = 0; e < D_; ++e) a[e] = b2[e];
#pragma unroll
  for (int f = 0; f < D_; ++f) {
    float hf = h[f];
#pragma unroll
    for (int e = 0; e < D_; ++e) a[e] = fmaf(hf, W2[f * D_ + e], a[e]);
  }
#pragma unroll
  for (int e = 0; e < D_; ++e) sG[m * D_ + e] = h[e] + fast_tanh(a[e]);  // G
  sBlk[m] = make_float4(blk[0], blk[1], blk[2], blk[3]);
  __syncthreads();
  if (threadIdx.x < 100) {
    int d = threadIdx.x & 3;
    int e = threadIdx.x >> 2;
    const float* sb = (const float*)sBlk;
    float sum = 0.0f;
    for (int mm = 0; mm < M_; ++mm)
      sum = fmaf(sb[mm * 4 + d], sG[mm * D_ + e], sum);
    acc_ws[atom * 100 + d * D_ + e] = sum * CSC;
  }
}

// K2: 8 atoms per block. DRt + fitting net fwd + bwd, emits Ei/Etot and dacc.
__global__ __launch_bounds__(256) void k_fit(
    const float* __restrict__ acc_ws,
    const float* __restrict__ fW0, const float* __restrict__ fb0,
    const float* __restrict__ fW1, const float* __restrict__ fb1,
    const float* __restrict__ fW2, const float* __restrict__ fb2,
    const float* __restrict__ fW3, const float* __restrict__ fb3,
    const float* __restrict__ ener_shift,
    float* __restrict__ dacc_ws, float* __restrict__ out) {
  constexpr int AB = 8;
  __shared__ float sAcc[AB][100];
  __shared__ float sX[AB][400];   // x fwd, then dx bwd
  __shared__ float sH0[AB][FH_];  // h0, then g0
  __shared__ float sT1[AB][FH_];  // tanh1, then g1
  __shared__ float sH1[AB][FH_];  // h1, then dh1
  __shared__ float sT2[AB][FH_];  // tanh2, then g2
  __shared__ float sEi[AB];
  int a0 = blockIdx.x * AB;
  int bb = a0 >> 10;
  int n0 = a0 & (N_ - 1);
  int t = (n0 >= 512) ? 1 : 0;
  int tid = threadIdx.x;
  for (int idx = tid; idx < AB * 100; idx += 256)
    ((float*)sAcc)[idx] = acc_ws[a0 * 100 + idx];
  if (tid < AB) sEi[tid] = 0.0f;
  __syncthreads();
  // DRt[e][f] = sum_d acc[d][e]*acc[d][f], f<16
  for (int idx = tid; idx < AB * 400; idx += 256) {
    int a = idx / 400; int r = idx % 400; int e = r >> 4; int f = r & 15;
    const float* A = sAcc[a];
    sX[a][r] = A[e] * A[f] + A[25 + e] * A[25 + f] + A[50 + e] * A[50 + f] +
               A[75 + e] * A[75 + f];
  }
  __syncthreads();
  const float* W0 = fW0 + t * 400 * FH_;
  const float* W1 = fW1 + t * FH_ * FH_;
  const float* W2 = fW2 + t * FH_ * FH_;
  const float* B0 = fb0 + t * FH_;
  const float* B1 = fb1 + t * FH_;
  const float* B2 = fb2 + t * FH_;
  const float* W3 = fW3 + t * FH_;
  int j = tid;
  if (j < FH_) {  // layer 0: 400 -> 240
    float acc8[AB];
#pragma unroll
    for (int a = 0; a < AB; ++a) acc8[a] = B0[j];
    for (int i = 0; i < 400; ++i) {
      float w = W0[i * FH_ + j];
#pragma unroll
      for (int a = 0; a < AB; ++a) acc8[a] = fmaf(sX[a][i], w, acc8[a]);
    }
#pragma unroll
    for (int a = 0; a < AB; ++a) sH0[a][j] = fast_tanh(acc8[a]);
  }
  __syncthreads();
  if (j < FH_) {  // layer 1 (residual)
    float acc8[AB];
#pragma unroll
    for (int a = 0; a < AB; ++a) acc8[a] = B1[j];
    for (int f = 0; f < FH_; ++f) {
      float w = W1[f * FH_ + j];
#pragma unroll
      for (int a = 0; a < AB; ++a) acc8[a] = fmaf(sH0[a][f], w, acc8[a]);
    }
#pragma unroll
    for (int a = 0; a < AB; ++a) {
      float tv = fast_tanh(acc8[a]);
      sT1[a][j] = tv;
      sH1[a][j] = sH0[a][j] + tv;
    }
  }
  __syncthreads();
  if (j < FH_) {  // layer 2 (residual) + Ei dot
    float acc8[AB];
#pragma unroll
    for (int a = 0; a < AB; ++a) acc8[a] = B2[j];
    for (int f = 0; f < FH_; ++f) {
      float w = W2[f * FH_ + j];
#pragma unroll
      for (int a = 0; a < AB; ++a) acc8[a] = fmaf(sH1[a][f], w, acc8[a]);
    }
    float w3 = W3[j];
#pragma unroll
    for (int a = 0; a < AB; ++a) {
      float tv = fast_tanh(acc8[a]);
      sT2[a][j] = tv;
      atomicAdd(&sEi[a], (sH1[a][j] + tv) * w3);
    }
  }
  __syncthreads();
  if (tid < AB) {
    float ei = sEi[tid] + fb3[t] + ener_shift[t];
    out[8 + a0 + tid] = ei;            // Ei
    atomicAdd(&out[bb], ei);           // Etot
  }
  if (j < FH_) {  // g2 = W3 * (1 - t2^2)   (dEi = 1)
    float w3 = W3[j];
#pragma unroll
    for (int a = 0; a < AB; ++a) {
      float tv = sT2[a][j];
      sT2[a][j] = w3 * (1.0f - tv * tv);
    }
  }
  __syncthreads();
  if (j < FH_) {  // dh1 = W3 + g2 @ W2^T ; g1 = dh1*(1-t1^2)
    float w3 = W3[j];
    float acc8[AB];
#pragma unroll
    for (int a = 0; a < AB; ++a) acc8[a] = w3;
    for (int k = 0; k < FH_; ++k) {
      float w = W2[j * FH_ + k];
#pragma unroll
      for (int a = 0; a < AB; ++a) acc8[a] = fmaf(sT2[a][k], w, acc8[a]);
    }
#pragma unroll
    for (int a = 0; a < AB; ++a) {
      float dh1 = acc8[a];
      float tv = sT1[a][j];
      sH1[a][j] = dh1;
      sT1[a][j] = dh1 * (1.0f - tv * tv);
    }
  }
  __syncthreads();
  if (j < FH_) {  // dh0 = dh1 + g1 @ W1^T ; g0 = dh0*(1-h0^2)
    float acc8[AB];
#pragma unroll
    for (int a = 0; a < AB; ++a) acc8[a] = sH1[a][j];
    for (int k = 0; k < FH_; ++k) {
      float w = W1[j * FH_ + k];
#pragma unroll
      for (int a = 0; a < AB; ++a) acc8[a] = fmaf(sT1[a][k], w, acc8[a]);
    }
#pragma unroll
    for (int a = 0; a < AB; ++a) {
      float h0v = sH0[a][j];
      sH0[a][j] = acc8[a] * (1.0f - h0v * h0v);
    }
  }
  __syncthreads();
  // dx = g0 @ W0^T  (overwrite sX)
  for (int i = tid; i < 400; i += 256) {
    float acc8[AB];
#pragma unroll
    for (int a = 0; a < AB; ++a) acc8[a] = 0.0f;
    for (int jj = 0; jj < FH_; ++jj) {
      float w = W0[i * FH_ + jj];
#pragma unroll
      for (int a = 0; a < AB; ++a) acc8[a] = fmaf(sH0[a][jj], w, acc8[a]);
    }
#pragma unroll
    for (int a = 0; a < AB; ++a) sX[a][i] = acc8[a];
  }
  __syncthreads();
  // dacc[d][e] = sum_{f<16} dDRt[e][f]*acc[d][f] + [e<16] sum_e2 dDRt[e2][e]*acc[d][e2]
  for (int idx = tid; idx < AB * 100; idx += 256) {
    int a = idx / 100; int r = idx % 100; int d = r / 25; int e = r % 25;
    const float* A = sAcc[a];
    const float* DX = sX[a];
    float sum = 0.0f;
#pragma unroll
    for (int f = 0; f < 16; ++f) sum = fmaf(DX[e * 16 + f], A[d * 25 + f], sum);
    if (e < 16) {
#pragma unroll
      for (int e2 = 0; e2 < 25; ++e2) sum = fmaf(DX[e2 * 16 + e], A[d * 25 + e2], sum);
    }
    dacc_ws[a0 * 100 + idx] = sum;
  }
}

// K3: per atom (block), per neighbor (thread), fwd+JVP through the embedding.
// R1 still spilled ~22 floats/thread (VGPR_Count=88, WRITE_SIZE=190MB): the
// allocator refuses a >~90-reg budget regardless of launch_bounds /
// waves_per_eu. Fix: stream (h, hp) through a PRIVATE LDS column per thread
// (float2 sHP[25][256], lane-consecutive -> conflict-free ds_*_b64), keeping
// only the 50 accumulator regs live; layer-2 outputs fold e-by-e straight
// into 5 scalar reductions. Peak live ~78 floats -> no scratch. No barriers:
// each column is thread-private (lgkmcnt orders same-thread LDS). 51.2KB LDS
// caps occupancy at 3 blocks/CU, which also RAISES the allocator's register
// budget (512/3waves ~ 170) — LDS is both spill store and budget signal.
__global__ __launch_bounds__(256) void k_bwd_force(
    const float* __restrict__ dR, const int* __restrict__ neigh,
    const float* __restrict__ davg, const float* __restrict__ dstd,
    const float* __restrict__ eW0, const float* __restrict__ eb0,
    const float* __restrict__ eW1, const float* __restrict__ eb1,
    const float* __restrict__ eW2, const float* __restrict__ eb2,
    const float* __restrict__ dacc_ws, float* __restrict__ out) {
  __shared__ float2 sHP[D_][256];   // (h, dh/ds) per layer, column = thread
  int atom = blockIdx.x;
  int bb = atom >> 10;
  int n = atom & (N_ - 1);
  int t = (n >= 512) ? 1 : 0;
  int m = threadIdx.x;
  int p = __builtin_amdgcn_readfirstlane(t * 2 + (m >> 7));
  const float* W0 = eW0 + p * D_;
  const float* b0 = eb0 + p * D_;
  const float* W1 = eW1 + p * D_ * D_;
  const float* b1 = eb1 + p * D_;
  const float* W2 = eW2 + p * D_ * D_;
  const float* b2 = eb2 + p * D_;
  const float* dac = dacc_ws + atom * 100;  // block-uniform -> scalar loads
  int base = atom * M_ + m;
  float dx = dR[base * 3 + 0];
  float dy = dR[base * 3 + 1];
  float dz = dR[base * 3 + 2];
  int nb = neigh[base];
  Geom g = geom_core(dx, dy, dz, nb);
  float blk[4], rsv[4];
  geom_blk(g, dx, dy, dz, t, m, davg, dstd, blk, rsv);

  // ---- layer 0: (h0, hp0) straight to LDS, nothing kept in regs ----
  float s = blk[0];
#pragma unroll
  for (int e = 0; e < D_; ++e) {
    float th = fast_tanh(fmaf(s, W0[e], b0[e]));
    sHP[e][m] = make_float2(th, (1.0f - th * th) * W0[e]);
  }
  // ---- layer 1 (residual): inputs streamed from LDS, 50 accum regs ----
  {
    float a[D_], ap[D_];
#pragma unroll
    for (int e = 0; e < D_; ++e) { a[e] = b1[e]; ap[e] = 0.0f; }
#pragma unroll
    for (int f = 0; f < D_; ++f) {
      float2 v = sHP[f][m];
#pragma unroll
      for (int e = 0; e < D_; ++e) {
        float w = W1[f * D_ + e];
        a[e] = fmaf(v.x, w, a[e]);
        ap[e] = fmaf(v.y, w, ap[e]);
      }
    }
#pragma unroll
    for (int e = 0; e < D_; ++e) {
      float2 old = sHP[e][m];
      float th = fast_tanh(a[e]);
      sHP[e][m] = make_float2(old.x + th,
                              fmaf(1.0f - th * th, ap[e], old.y));
    }
  }
  // ---- layer 2 (residual): outputs folded e-by-e into 5 scalars ----
  float ds = 0.0f, db0 = 0.0f, db1 = 0.0f, db2 = 0.0f, db3 = 0.0f;
  {
    float a[D_], ap[D_];
#pragma unroll
    for (int e = 0; e < D_; ++e) { a[e] = b2[e]; ap[e] = 0.0f; }
#pragma unroll
    for (int f = 0; f < D_; ++f) {
      float2 v = sHP[f][m];
#pragma unroll
      for (int e = 0; e < D_; ++e) {
        float w = W2[f * D_ + e];
        a[e] = fmaf(v.x, w, a[e]);
        ap[e] = fmaf(v.y, w, ap[e]);
      }
    }
#pragma unroll
    for (int e = 0; e < D_; ++e) {
      float2 old = sHP[e][m];
      float th = fast_tanh(a[e]);
      float G = old.x + th;                              // final G[e]
      float hp2 = fmaf(1.0f - th * th, ap[e], old.y);    // dG[e]/ds
      float d0 = dac[e], d1 = dac[25 + e], d2 = dac[50 + e], d3 = dac[75 + e];
      float u = d0 * blk[0] + d1 * blk[1] + d2 * blk[2] + d3 * blk[3];
      ds = fmaf(u, hp2, ds);
      db0 = fmaf(d0, G, db0);
      db1 = fmaf(d1, G, db1);
      db2 = fmaf(d2, G, db2);
      db3 = fmaf(d3, G, db3);
    }
  }
  float dE0 = (db0 + ds) * CSC;
  float dE1 = db1 * CSC, dE2 = db2 * CSC, dE3 = db3 * CSC;

  // ---- fold the 4x3 geometry Jacobian directly into the force vector ----
  float dv[3] = {dx, dy, dz};
  float pre1[3] = {dx * g.inr2, dy * g.inr2, dz * g.inr2};
  float ci = g.dvv * g.inr;
  float com[3];
#pragma unroll
  for (int c = 0; c < 3; ++c) com[c] = ci * dv[c];
  float iv = g.inr3 * g.vv;
  float pc[3];
  float f0 = dE0 * rsv[0];
#pragma unroll
  for (int c = 0; c < 3; ++c) pc[c] = f0 * (dv[c] * iv - g.inr * com[c]);
  float dEr[3] = {dE1, dE2, dE3};
#pragma unroll
  for (int r = 0; r < 3; ++r) {
    float fr = dEr[r] * rsv[1 + r];
#pragma unroll
    for (int c = 0; c < 3; ++c) {
      float outer = 2.0f * dv[r] * dv[c] * g.inr4 - ((r == c) ? g.inr2 : 0.0f);
      pc[c] = fmaf(fr, outer * g.vv - pre1[r] * com[c], pc[c]);
    }
  }
  float px = pc[0] * g.mf, py = pc[1] * g.mf, pz = pc[2] * g.mf;

  if (nb > 0) {  // scatter to neighbor j = nb-1
    int jn = nb - 1;
    int fi = 8 + NATOM + (bb * N_ + jn) * 3;
    atomicAdd(&out[fi + 0], px);
    atomicAdd(&out[fi + 1], py);
    atomicAdd(&out[fi + 2], pz);
  }
  // F_self: 64-lane shuffle reduce, one atomic per wave per component
#pragma unroll
  for (int i = 1; i < 64; i <<= 1) {
    px += __shfl_xor(px, i);
    py += __shfl_xor(py, i);
    pz += __shfl_xor(pz, i);
  }
  if ((m & 63) == 0) {
    int fi = 8 + NATOM + atom * 3;
    atomicAdd(&out[fi + 0], -px);
    atomicAdd(&out[fi + 1], -py);
    atomicAdd(&out[fi + 2], -pz);
  }
}

}  // namespace

extern "C" void kernel_launch(void* const* d_in, const int* in_sizes, int n_in,
                              void* d_out, int out_size, void* d_ws, size_t ws_size,
                              hipStream_t stream) {
  (void)in_sizes; (void)n_in; (void)ws_size;
  const float* image_dR   = (const float*)d_in[0];
  const int*   list_neigh = (const int*)d_in[1];
  const float* davg       = (const float*)d_in[2];
  const float* dstd       = (const float*)d_in[3];
  const float* eW0        = (const float*)d_in[4];
  const float* eb0        = (const float*)d_in[5];
  const float* eW1        = (const float*)d_in[6];
  const float* eb1        = (const float*)d_in[7];
  const float* eW2        = (const float*)d_in[8];
  const float* eb2        = (const float*)d_in[9];
  const float* fW0        = (const float*)d_in[10];
  const float* fb0        = (const float*)d_in[11];
  const float* fW1        = (const float*)d_in[12];
  const float* fb1        = (const float*)d_in[13];
  const float* fW2        = (const float*)d_in[14];
  const float* fb2        = (const float*)d_in[15];
  const float* fW3        = (const float*)d_in[16];
  const float* fb3        = (const float*)d_in[17];
  const float* ener_shift = (const float*)d_in[18];
  float* out = (float*)d_out;
  float* acc_ws  = (float*)d_ws;                  // 8192*100 floats
  float* dacc_ws = acc_ws + NATOM * 100;          // 8192*100 floats

  hipMemsetAsync(d_out, 0, (size_t)out_size * sizeof(float), stream);
  k_embed_acc<<<NATOM, 256, 0, stream>>>(image_dR, list_neigh, davg, dstd,
                                         eW0, eb0, eW1, eb1, eW2, eb2, acc_ws);
  k_fit<<<NATOM / 8, 256, 0, stream>>>(acc_ws, fW0, fb0, fW1, fb1, fW2, fb2,
                                       fW3, fb3, ener_shift, dacc_ws, out);
  k_bwd_force<<<NATOM, 256, 0, stream>>>(image_dR, list_neigh, davg, dstd,
                                         eW0, eb0, eW1, eb1, eW2, eb2,
                                         dacc_ws, out);
}